// Round 9
// baseline (123.159 us; speedup 1.0000x reference)
//
#include <hip/hip_runtime.h>

#define EPS 1e-12f

// MovingAvgNormNonBias: x [B=32, T=3000, D=512] fp32, k=100.
// Two-pass (R6 structure, proven fastest):
//   k1: 25-row segment sums (s1, s2) per (b, seg, d4-col) into d_ws. 7680 waves.
//   k2: 512-thread blocks = 8 waves = 4 adjacent 25-row chunks x 2 D-halves,
//       all on ONE CU. Each wave: init from 4 ws segment sums (no barrier),
//       then the pipelined streaming loop. Cross-chunk row sharing: wave q's
//       in-rows == wave q+2's numerator rows (1 step later), out-rows ==
//       wave q-2's numerator rows -- per-step block working set ~24 KB -> L1.
// XCD swizzle: adjacent groups of one batch on one XCD for boundary-strip L2 hits.

typedef float f4 __attribute__((ext_vector_type(4)));

constexpr int Bq = 32, Tq = 3000, Dq = 512;
constexpr int SEGR = 25;             // rows per chunk
constexpr int NSEG = Tq / SEGR;      // 120
constexpr int WT = 4;                // chunks per mavn block
constexpr int TB = SEGR * WT;        // 100 rows per mavn block
constexpr int NGRP = Tq / TB;        // 30 groups per batch
constexpr int NBm = Bq * NGRP;       // 960 mavn blocks
constexpr int NXCD = 8;

__global__ __launch_bounds__(128) void seg_sums_kernel(
    const float* __restrict__ x, float* __restrict__ ws)
{
    const int s = blockIdx.x;          // segment 0..NSEG-1
    const int b = blockIdx.y;
    const int d4 = threadIdx.x;        // 0..127
    const float* xp = x + ((size_t)b * Tq) * Dq + (size_t)d4 * 4;

    f4 a1 = {0.f, 0.f, 0.f, 0.f};
    f4 a2 = a1, b1 = a1, b2 = a1;
    const int r0 = s * SEGR;
#pragma unroll 5
    for (int j = 0; j < SEGR; j += 2) {
        const f4 v = *(const f4*)(xp + (size_t)(r0 + j) * Dq);
        a1 += v; a2 += v * v;
        if (j + 1 < SEGR) {
            const f4 w = *(const f4*)(xp + (size_t)(r0 + j + 1) * Dq);
            b1 += w; b2 += w * w;
        }
    }
    f4* w1 = (f4*)ws;                          // [B][NSEG][128]
    f4* w2 = w1 + (size_t)Bq * NSEG * (Dq / 4);
    const size_t idx = ((size_t)b * NSEG + s) * (Dq / 4) + d4;
    w1[idx] = a1 + b1;
    w2[idx] = a2 + b2;
}

__global__ __launch_bounds__(512, 8) void mavn_kernel(
    const float* __restrict__ x, const int* __restrict__ kptr,
    float* __restrict__ out, const float* __restrict__ ws, int use_seg)
{
    // XCD-swizzled decode: adjacent slots -> adjacent row-groups, same batch
    const int g = blockIdx.x;                  // 0..NBm-1
    const int xcd = g & (NXCD - 1);
    const int slot = g >> 3;
    const int pair = xcd * (NBm / NXCD) + slot;
    const int b = pair / NGRP;
    const int grp = pair % NGRP;

    const int tid = threadIdx.x;
    const int w = tid >> 6;             // wave 0..7
    const int l = tid & 63;
    const int q = w >> 1;               // 0..3: chunk within block
    const int dh = w & 1;               // 0..1: D-half

    const int c = grp * WT + q;         // global chunk index
    const int t0 = c * SEGR;
    const int t1 = t0 + SEGR;

    const int k = kptr[0];
    const int half = k >> 1;
    const size_t bbase = (size_t)b * Tq * Dq;
    const int doff = dh * (Dq / 2) + l * 4;
    const float* xp = x + bbase + doff;
    float* op = out + bbase + doff;

    const float kf = (float)k;
    const float inv_km1 = 1.0f / (float)(k - 1);
    const int tail_start = Tq - (k - half);

    const bool seg_ok = use_seg && (k == 4 * SEGR);
    // interior: full window in-bounds AND denom == k for every t in chunk
    const bool interior = seg_ok && (t0 >= half) &&
                          (t0 + SEGR - 1 + (k - half) - 1 <= Tq - 1) &&
                          (t0 + SEGR - 1 < tail_start);

    if (interior) {
        // init from ws segment sums: window [t0-50, t0+49] = segs c-2..c+1
        const f4* w1 = (const f4*)ws;
        const f4* w2 = w1 + (size_t)Bq * NSEG * (Dq / 4);
        const int colf4 = dh * (Dq / 8) + l;     // dh*64 + l
        f4 s1 = {0.f, 0.f, 0.f, 0.f};
        f4 s2 = s1;
#pragma unroll
        for (int i = 0; i < 4; ++i) {
            const size_t idx = ((size_t)b * NSEG + (c - 2 + i)) * (Dq / 4) + colf4;
            s1 += w1[idx];
            s2 += w2[idx];
        }
        const float inv_k = 1.0f / kf;
        // peel j = 0
        {
            const f4 xc = *(const f4*)(xp + (size_t)t0 * Dq);
            f4 o;
#pragma unroll
            for (int cc = 0; cc < 4; ++cc) {
                const float m = s1[cc] * inv_k;
                float var_sum = s2[cc] - m * s1[cc];
                var_sum = fmaxf(var_sum, 1e-12f);
                const float r = __builtin_amdgcn_rsqf(var_sum * inv_km1);
                o[cc] = (xc[cc] - m) * r;
            }
            __builtin_nontemporal_store(o, (f4*)(op + (size_t)t0 * Dq));
        }
        // 2x-unrolled pipelined j = 1..24 (12 exact pairs)
        const int inoff = (k - half) - 1;      // +49
        const int oboff = -(half + 1);         // -51
        f4 n0 = *(const f4*)(xp + (size_t)(t0 + 1) * Dq);
        f4 n1 = *(const f4*)(xp + (size_t)(t0 + 2) * Dq);
        f4 i0 = *(const f4*)(xp + (size_t)(t0 + 1 + inoff) * Dq);
        f4 i1 = *(const f4*)(xp + (size_t)(t0 + 2 + inoff) * Dq);
        f4 o0 = *(const f4*)(xp + (size_t)(t0 + 1 + oboff) * Dq);
        f4 o1 = *(const f4*)(xp + (size_t)(t0 + 2 + oboff) * Dq);
        for (int j = 1; j < SEGR; j += 2) {
            const f4 cn0 = n0, cn1 = n1, ci0 = i0, ci1 = i1, co0 = o0, co1 = o1;
            {
                const int jn = (j + 2 <= SEGR - 2) ? j + 2 : j;  // tail: reload (L1-hot)
                n0 = *(const f4*)(xp + (size_t)(t0 + jn) * Dq);
                n1 = *(const f4*)(xp + (size_t)(t0 + jn + 1) * Dq);
                i0 = *(const f4*)(xp + (size_t)(t0 + jn + inoff) * Dq);
                i1 = *(const f4*)(xp + (size_t)(t0 + jn + 1 + inoff) * Dq);
                o0 = *(const f4*)(xp + (size_t)(t0 + jn + oboff) * Dq);
                o1 = *(const f4*)(xp + (size_t)(t0 + jn + 1 + oboff) * Dq);
            }
            // step j
            s1 += ci0 - co0;
            s2 += ci0 * ci0 - co0 * co0;
            f4 oa;
#pragma unroll
            for (int cc = 0; cc < 4; ++cc) {
                const float m = s1[cc] * inv_k;
                float var_sum = s2[cc] - m * s1[cc];
                var_sum = fmaxf(var_sum, 1e-12f);
                const float r = __builtin_amdgcn_rsqf(var_sum * inv_km1);
                oa[cc] = (cn0[cc] - m) * r;
            }
            __builtin_nontemporal_store(oa, (f4*)(op + (size_t)(t0 + j) * Dq));
            // step j+1
            s1 += ci1 - co1;
            s2 += ci1 * ci1 - co1 * co1;
            f4 ob2;
#pragma unroll
            for (int cc = 0; cc < 4; ++cc) {
                const float m = s1[cc] * inv_k;
                float var_sum = s2[cc] - m * s1[cc];
                var_sum = fmaxf(var_sum, 1e-12f);
                const float r = __builtin_amdgcn_rsqf(var_sum * inv_km1);
                ob2[cc] = (cn1[cc] - m) * r;
            }
            __builtin_nontemporal_store(ob2, (f4*)(op + (size_t)(t0 + j + 1) * Dq));
        }
        return;
    }

    // ---- general (edge / k!=100 / no-ws) path: inline init + masked loop ----
    f4 s1 = {0.f, 0.f, 0.f, 0.f};
    f4 s2 = s1;
    {
        const int wlo = (t0 - half > 0) ? t0 - half : 0;
        const int whi = (t0 + (k - half) < Tq) ? t0 + (k - half) : Tq;
        f4 a1 = s1, a2 = s1;
        int j = wlo;
        for (; j + 1 < whi; j += 2) {
            const f4 v = *(const f4*)(xp + (size_t)j * Dq);
            const f4 u = *(const f4*)(xp + (size_t)(j + 1) * Dq);
            s1 += v; s2 += v * v;
            a1 += u; a2 += u * u;
        }
        if (j < whi) {
            const f4 v = *(const f4*)(xp + (size_t)j * Dq);
            s1 += v; s2 += v * v;
        }
        s1 += a1; s2 += a2;
    }

    f4 nx = *(const f4*)(xp + (size_t)t0 * Dq);
    f4 ia = {0.f, 0.f, 0.f, 0.f};
    f4 ob = ia;
    float wa = 0.f, wb = 0.f;

    for (int t = t0; t < t1; ++t) {
        const f4 cnum = nx;
        const f4 cin = ia;
        const f4 cout = ob;
        const float cwa = wa, cwb = wb;

        {
            const int tn = (t + 1 < t1) ? t + 1 : t;
            nx = *(const f4*)(xp + (size_t)tn * Dq);
            int ja = tn + (k - half) - 1;
            int jr = tn - half - 1;
            wa = (ja < Tq && tn > t0) ? 1.f : 0.f;
            wb = (jr >= 0 && tn > t0) ? 1.f : 0.f;
            ja = ja < Tq - 1 ? ja : Tq - 1; ja = ja > 0 ? ja : 0;
            jr = jr > 0 ? jr : 0;
            ia = *(const f4*)(xp + (size_t)ja * Dq);
            ob = *(const f4*)(xp + (size_t)jr * Dq);
        }

        s1 += cwa * cin - cwb * cout;
        s2 += cwa * cin * cin - cwb * cout * cout;

        // branchless denom: ramp half..k-1, flat k, ramp k-1..half
        int idn = half + t;
        idn = idn < k ? idn : k;
        const int tail = (k - 1) - (t - tail_start);
        idn = idn < tail ? idn : tail;
        const float inv_denom = __builtin_amdgcn_rcpf((float)idn);

        f4 o;
#pragma unroll
        for (int cc = 0; cc < 4; ++cc) {
            const float m = s1[cc] * inv_denom;
            float var_sum = s2[cc] - 2.0f * m * s1[cc] + kf * m * m;
            var_sum = fmaxf(var_sum, 0.0f);
            const float sd = __builtin_amdgcn_sqrtf(var_sum * inv_km1);
            o[cc] = (cnum[cc] - m) * __builtin_amdgcn_rcpf(sd + EPS);
        }
        __builtin_nontemporal_store(o, (f4*)(op + (size_t)t * Dq));
    }
}

extern "C" void kernel_launch(void* const* d_in, const int* in_sizes, int n_in,
                              void* d_out, int out_size, void* d_ws, size_t ws_size,
                              hipStream_t stream) {
    const float* x = (const float*)d_in[0];
    const int* kptr = (const int*)d_in[1];
    float* out = (float*)d_out;
    (void)in_sizes; (void)n_in; (void)out_size;

    const size_t ws_need = 2ull * Bq * NSEG * Dq * sizeof(float);  // 15.7 MB
    const int use_seg = (d_ws != nullptr && ws_size >= ws_need) ? 1 : 0;

    if (use_seg) {
        dim3 g1(NSEG, Bq);
        seg_sums_kernel<<<g1, 128, 0, stream>>>(x, (float*)d_ws);
    }
    mavn_kernel<<<NBm, 512, 0, stream>>>(x, kptr, out, (const float*)d_ws, use_seg);
}

// Round 10
// 106.353 us; speedup vs baseline: 1.1580x; 1.1580x over previous
//
#include <hip/hip_runtime.h>

#define EPS 1e-12f

// MovingAvgNormNonBias: x [B=32, T=3000, D=512] fp32, k=100.
// Two-pass:
//   k1: 25-row segment sums (s1,s2) per (b,seg,d4-col) into d_ws (7680 waves,
//       HBM-BW-bound, ~floor).
//   k2: 128-thr blocks (2 waves), one 25-row chunk per block. Interior path
//       streams the 3 row-streams (num/in/out) via global_load_lds into a
//       per-wave double-buffered LDS ring with counted vmcnt waits (T3/T4):
//       in-flight bytes come from LDS, not VGPRs -> ~72 KB/CU outstanding vs
//       3 KB with register prefetch. No __syncthreads (wave-private ring).
// XCD swizzle keeps adjacent chunks of one batch on one XCD.

typedef float f4 __attribute__((ext_vector_type(4)));

constexpr int Bq = 32, Tq = 3000, Dq = 512;
constexpr int SEGR = 25;             // rows per chunk
constexpr int NSEG = Tq / SEGR;      // 120
constexpr int NCHUNK = Tq / SEGR;    // 120
constexpr int NBm = Bq * NCHUNK;     // 3840 mavn blocks
constexpr int NXCD = 8;

__device__ __forceinline__ void gl_lds16(const float* g, float* l) {
    __builtin_amdgcn_global_load_lds(
        (const __attribute__((address_space(1))) void*)g,
        (__attribute__((address_space(3))) void*)l, 16, 0, 0);
}

__global__ __launch_bounds__(128) void seg_sums_kernel(
    const float* __restrict__ x, float* __restrict__ ws)
{
    const int s = blockIdx.x;          // segment 0..NSEG-1
    const int b = blockIdx.y;
    const int d4 = threadIdx.x;        // 0..127
    const float* xp = x + ((size_t)b * Tq) * Dq + (size_t)d4 * 4;

    f4 a1 = {0.f, 0.f, 0.f, 0.f};
    f4 a2 = a1, b1 = a1, b2 = a1;
    const int r0 = s * SEGR;
#pragma unroll 5
    for (int j = 0; j < SEGR; j += 2) {
        const f4 v = *(const f4*)(xp + (size_t)(r0 + j) * Dq);
        a1 += v; a2 += v * v;
        if (j + 1 < SEGR) {
            const f4 w = *(const f4*)(xp + (size_t)(r0 + j + 1) * Dq);
            b1 += w; b2 += w * w;
        }
    }
    f4* w1 = (f4*)ws;                          // [B][NSEG][128]
    f4* w2 = w1 + (size_t)Bq * NSEG * (Dq / 4);
    const size_t idx = ((size_t)b * NSEG + s) * (Dq / 4) + d4;
    w1[idx] = a1 + b1;
    w2[idx] = a2 + b2;
}

__global__ __launch_bounds__(128, 2) void mavn_kernel(
    const float* __restrict__ x, const int* __restrict__ kptr,
    float* __restrict__ out, const float* __restrict__ ws, int use_seg)
{
    // per-wave LDS ring: [wave][buf][row-in-group][stream][64 lanes * f4]
    __shared__ float ring[2][2][3][3][256];    // 36 KB

    // XCD-swizzled decode of (b, chunk)
    const int g = blockIdx.x;                  // 0..NBm-1
    const int xcd = g & (NXCD - 1);
    const int slot = g >> 3;
    const int pair = xcd * (NBm / NXCD) + slot;
    const int b = pair / NCHUNK;
    const int c = pair % NCHUNK;
    const int t0 = c * SEGR;
    const int t1 = t0 + SEGR;

    const int k = kptr[0];
    const int half = k >> 1;
    const int tid = threadIdx.x;
    const int w = tid >> 6;                    // wave 0..1
    const int l4 = (tid & 63) * 4;
    const size_t base = ((size_t)b * Tq) * (size_t)Dq + (size_t)tid * 4;
    const float* xp = x + base;
    float* op = out + base;

    const float kf = (float)k;
    const float inv_km1 = 1.0f / (float)(k - 1);
    const int tail_start = Tq - (k - half);

    const bool seg_ok = use_seg && (k == 4 * SEGR);
    const bool interior = seg_ok && (t0 >= half) &&
                          (t0 + SEGR - 1 + (k - half) - 1 <= Tq - 1) &&
                          (t0 + SEGR - 1 < tail_start);

    if (interior) {
        // init from ws segment sums: window [t0-50, t0+49] = segs c-2..c+1
        const f4* w1 = (const f4*)ws;
        const f4* w2 = w1 + (size_t)Bq * NSEG * (Dq / 4);
        f4 s1 = {0.f, 0.f, 0.f, 0.f};
        f4 s2 = s1;
#pragma unroll
        for (int i = 0; i < 4; ++i) {
            const size_t idx = ((size_t)b * NSEG + (c - 2 + i)) * (Dq / 4) + tid;
            s1 += w1[idx];
            s2 += w2[idx];
        }
        const float inv_k = 1.0f / kf;
        // peel j = 0 (older vmem ops only strengthen later counted waits)
        {
            const f4 xc = *(const f4*)(xp + (size_t)t0 * Dq);
            f4 o;
#pragma unroll
            for (int cc = 0; cc < 4; ++cc) {
                const float m = s1[cc] * inv_k;
                float var_sum = s2[cc] - m * s1[cc];
                var_sum = fmaxf(var_sum, 1e-12f);
                const float r = __builtin_amdgcn_rsqf(var_sum * inv_km1);
                o[cc] = (xc[cc] - m) * r;
            }
            __builtin_nontemporal_store(o, (f4*)(op + (size_t)t0 * Dq));
        }

        const int inoff = (k - half) - 1;      // +49
        const int oboff = -(half + 1);         // -51

        // stage group g (3 steps) into buf: 9 global_load_lds, 16 B/lane
        auto stage = [&](int buf, int grp) {
#pragma unroll
            for (int r = 0; r < 3; ++r) {
                int j = 1 + 3 * grp + r;
                j = (j <= SEGR - 1) ? j : SEGR - 1;     // clamp (dummy tail group)
                const float* pn = xp + (size_t)(t0 + j) * Dq;
                const float* pi = xp + (size_t)(t0 + j + inoff) * Dq;
                const float* po = xp + (size_t)(t0 + j + oboff) * Dq;
                gl_lds16(pn, &ring[w][buf][r][0][0]);
                gl_lds16(pi, &ring[w][buf][r][1][0]);
                gl_lds16(po, &ring[w][buf][r][2][0]);
            }
        };
        // compute group g (3 steps) from buf: ds_read + math + nt-store (3 stores)
        auto compute = [&](int buf, int grp) {
#pragma unroll
            for (int r = 0; r < 3; ++r) {
                const int j = 1 + 3 * grp + r;
                const f4 cn = *(const f4*)&ring[w][buf][r][0][l4];
                const f4 ci = *(const f4*)&ring[w][buf][r][1][l4];
                const f4 co = *(const f4*)&ring[w][buf][r][2][l4];
                s1 += ci - co;
                s2 += ci * ci - co * co;
                f4 o;
#pragma unroll
                for (int cc = 0; cc < 4; ++cc) {
                    const float m = s1[cc] * inv_k;
                    float var_sum = s2[cc] - m * s1[cc];
                    var_sum = fmaxf(var_sum, 1e-12f);
                    const float r2 = __builtin_amdgcn_rsqf(var_sum * inv_km1);
                    o[cc] = (cn[cc] - m) * r2;
                }
                __builtin_nontemporal_store(o, (f4*)(op + (size_t)(t0 + j) * Dq));
            }
        };

        // prologue: group 0 in flight
        stage(0, 0);
        // body 0: after group-0's 9 loads, exactly 9 newer ops (stage g1) -> vmcnt(9)
        stage(1, 1);
        asm volatile("s_waitcnt vmcnt(9)" ::: "memory");
        __builtin_amdgcn_sched_barrier(0);
        compute(0, 0);
        asm volatile("" ::: "memory");   // pin: reads of buf0 precede any later stage into buf0
        // bodies 1..7: after group-g's loads (staged in body g-1):
        //   3 stores (body g-1) + 9 loads (body g stage) = 12 -> vmcnt(12)
        // body 7 stages a clamped dummy group to keep the count uniform.
#pragma unroll
        for (int gg = 1; gg < 8; ++gg) {
            stage((gg + 1) & 1, gg + 1);
            asm volatile("s_waitcnt vmcnt(12)" ::: "memory");
            __builtin_amdgcn_sched_barrier(0);
            compute(gg & 1, gg);
            asm volatile("" ::: "memory");
        }
        return;
    }

    // ---- general (edge / k!=100 / no-ws) path: inline init + masked loop ----
    f4 s1 = {0.f, 0.f, 0.f, 0.f};
    f4 s2 = s1;
    {
        const int wlo = (t0 - half > 0) ? t0 - half : 0;
        const int whi = (t0 + (k - half) < Tq) ? t0 + (k - half) : Tq;
        f4 a1 = s1, a2 = s1;
        int j = wlo;
        for (; j + 1 < whi; j += 2) {
            const f4 v = *(const f4*)(xp + (size_t)j * Dq);
            const f4 u = *(const f4*)(xp + (size_t)(j + 1) * Dq);
            s1 += v; s2 += v * v;
            a1 += u; a2 += u * u;
        }
        if (j < whi) {
            const f4 v = *(const f4*)(xp + (size_t)j * Dq);
            s1 += v; s2 += v * v;
        }
        s1 += a1; s2 += a2;
    }

    f4 nx = *(const f4*)(xp + (size_t)t0 * Dq);
    f4 ia = {0.f, 0.f, 0.f, 0.f};
    f4 ob = ia;
    float wa = 0.f, wb = 0.f;

    for (int t = t0; t < t1; ++t) {
        const f4 cnum = nx;
        const f4 cin = ia;
        const f4 cout = ob;
        const float cwa = wa, cwb = wb;

        {
            const int tn = (t + 1 < t1) ? t + 1 : t;
            nx = *(const f4*)(xp + (size_t)tn * Dq);
            int ja = tn + (k - half) - 1;
            int jr = tn - half - 1;
            wa = (ja < Tq && tn > t0) ? 1.f : 0.f;
            wb = (jr >= 0 && tn > t0) ? 1.f : 0.f;
            ja = ja < Tq - 1 ? ja : Tq - 1; ja = ja > 0 ? ja : 0;
            jr = jr > 0 ? jr : 0;
            ia = *(const f4*)(xp + (size_t)ja * Dq);
            ob = *(const f4*)(xp + (size_t)jr * Dq);
        }

        s1 += cwa * cin - cwb * cout;
        s2 += cwa * cin * cin - cwb * cout * cout;

        int idn = half + t;
        idn = idn < k ? idn : k;
        const int tail = (k - 1) - (t - tail_start);
        idn = idn < tail ? idn : tail;
        const float inv_denom = __builtin_amdgcn_rcpf((float)idn);

        f4 o;
#pragma unroll
        for (int cc = 0; cc < 4; ++cc) {
            const float m = s1[cc] * inv_denom;
            float var_sum = s2[cc] - 2.0f * m * s1[cc] + kf * m * m;
            var_sum = fmaxf(var_sum, 0.0f);
            const float sd = __builtin_amdgcn_sqrtf(var_sum * inv_km1);
            o[cc] = (cnum[cc] - m) * __builtin_amdgcn_rcpf(sd + EPS);
        }
        __builtin_nontemporal_store(o, (f4*)(op + (size_t)t * Dq));
    }
}

extern "C" void kernel_launch(void* const* d_in, const int* in_sizes, int n_in,
                              void* d_out, int out_size, void* d_ws, size_t ws_size,
                              hipStream_t stream) {
    const float* x = (const float*)d_in[0];
    const int* kptr = (const int*)d_in[1];
    float* out = (float*)d_out;
    (void)in_sizes; (void)n_in; (void)out_size;

    const size_t ws_need = 2ull * Bq * NSEG * Dq * sizeof(float);  // 15.7 MB
    const int use_seg = (d_ws != nullptr && ws_size >= ws_need) ? 1 : 0;

    if (use_seg) {
        dim3 g1(NSEG, Bq);
        seg_sums_kernel<<<g1, 128, 0, stream>>>(x, (float*)d_ws);
    }
    mavn_kernel<<<NBm, 128, 0, stream>>>(x, kptr, out, (const float*)d_ws, use_seg);
}